// Round 25
// baseline (296.818 us; speedup 1.0000x reference)
//
#include <hip/hip_runtime.h>
#include <hip/hip_fp16.h>

#define N_NODES 50000
#define N_EDGES 1600000
#define F_IN    128
#define EMB     48
#define HID     48
#define OUTF    64
#define KCH     7
#define TPAD    64                   // padded T row length (halves) = 128 B
#define KSL     14                   // K-slices of 32 over 7*64 stacked T

#define NR    8                      // node ranges (LDS partitions)
#define RANGE (N_NODES / NR)         // 6250 counters
#define BPR   64                     // edge slices
#define SLICE (N_EDGES / BPR)        // 25000 edges per slice (div by 4)
#define HTHREADS 512
#define NBLK  ((N_NODES + 255) / 256)   // 196 blocks over nodes
#define NTILES (N_NODES / 16)        // 3125 node tiles

typedef __attribute__((ext_vector_type(8))) _Float16 half8;
typedef __attribute__((ext_vector_type(4))) float f32x4;

// ---- packed 4B edge record: low 16 = src (u16), high 16 = norm (f16) ----
__device__ __forceinline__ float dec_norm(unsigned er) {
    unsigned short h = (unsigned short)(er >> 16);
    return __half2float(*reinterpret_cast<__half*>(&h));
}

// ---- gather+accumulate (lane<12 only), unroll-16 / 4 / scalar ----
#define PROP_GATHER_LOOP(TSRC)                                                  \
    {                                                                           \
        int e16 = s + ((e - s) & ~15);                                          \
        for (; p < e16; p += 16) {                                              \
            float ww[16]; uint2 hv[16];                                         \
            _Pragma("unroll")                                                   \
            for (int j = 0; j < 16; ++j) {                                      \
                unsigned er = edges[p + j];                                     \
                ww[j] = dec_norm(er);                                           \
                hv[j] = *reinterpret_cast<const uint2*>(                        \
                    TSRC + (size_t)(er & 0xFFFFu) * TPAD + 4 * lane);           \
            }                                                                   \
            _Pragma("unroll")                                                   \
            for (int j = 0; j < 16; ++j) {                                      \
                __half2 h01 = *reinterpret_cast<__half2*>(&hv[j].x);            \
                __half2 h23 = *reinterpret_cast<__half2*>(&hv[j].y);            \
                a0 += ww[j] * __low2float(h01);                                 \
                a1 += ww[j] * __high2float(h01);                                \
                a2 += ww[j] * __low2float(h23);                                 \
                a3 += ww[j] * __high2float(h23);                                \
            }                                                                   \
        }                                                                       \
        int e4b = p + ((e - p) & ~3);                                           \
        for (; p < e4b; p += 4) {                                               \
            float ww[4]; uint2 hv[4];                                           \
            _Pragma("unroll")                                                   \
            for (int j = 0; j < 4; ++j) {                                       \
                unsigned er = edges[p + j];                                     \
                ww[j] = dec_norm(er);                                           \
                hv[j] = *reinterpret_cast<const uint2*>(                        \
                    TSRC + (size_t)(er & 0xFFFFu) * TPAD + 4 * lane);           \
            }                                                                   \
            _Pragma("unroll")                                                   \
            for (int j = 0; j < 4; ++j) {                                       \
                __half2 h01 = *reinterpret_cast<__half2*>(&hv[j].x);            \
                __half2 h23 = *reinterpret_cast<__half2*>(&hv[j].y);            \
                a0 += ww[j] * __low2float(h01);                                 \
                a1 += ww[j] * __high2float(h01);                                \
                a2 += ww[j] * __low2float(h23);                                 \
                a3 += ww[j] * __high2float(h23);                                \
            }                                                                   \
        }                                                                       \
        for (; p < e; ++p) {                                                    \
            unsigned er = edges[p];                                             \
            float wv = dec_norm(er);                                            \
            uint2 hv = *reinterpret_cast<const uint2*>(                         \
                TSRC + (size_t)(er & 0xFFFFu) * TPAD + 4 * lane);               \
            __half2 h01 = *reinterpret_cast<__half2*>(&hv.x);                   \
            __half2 h23 = *reinterpret_cast<__half2*>(&hv.y);                   \
            a0 += wv * __low2float(h01);                                        \
            a1 += wv * __high2float(h01);                                       \
            a2 += wv * __low2float(h23);                                        \
            a3 += wv * __high2float(h23);                                       \
        }                                                                       \
    }

// ---- pass A: partitioned LDS histogram; ALSO records per-edge rank (u16) ----
__global__ __launch_bounds__(HTHREADS) void hist_part_kernel(
    const int* __restrict__ row, const int* __restrict__ col,
    const float* __restrict__ w,
    unsigned short* __restrict__ pc, float* __restrict__ pd,
    unsigned short* __restrict__ rank16)
{
    __shared__ unsigned lc32[RANGE / 2];  // 12.5 KB
    __shared__ float    ld[RANGE];        // 25 KB
    int t = threadIdx.x;
    for (int i = t; i < RANGE / 2; i += HTHREADS) lc32[i] = 0u;
    for (int i = t; i < RANGE; i += HTHREADS) ld[i] = 0.f;
    __syncthreads();
    int r = blockIdx.x / BPR;        // node range
    int b = blockIdx.x % BPR;        // edge slice
    int base = r * RANGE;
    int lo = b * SLICE;
    for (int e0 = lo + t * 4; e0 < lo + SLICE; e0 += HTHREADS * 4) {
        int4   c4 = *(const int4*)&col[e0];
        int4   r4 = *(const int4*)&row[e0];
        float4 w4 = *(const float4*)&w[e0];
        #pragma unroll
        for (int j = 0; j < 4; ++j) {
            int c  = (j == 0) ? c4.x : (j == 1) ? c4.y : (j == 2) ? c4.z : c4.w;
            int rw = (j == 0) ? r4.x : (j == 1) ? r4.y : (j == 2) ? r4.z : r4.w;
            float we = (j == 0) ? w4.x : (j == 1) ? w4.y : (j == 2) ? w4.z : w4.w;
            int ci = c - base;
            if ((unsigned)ci < RANGE) {
                unsigned sh = (ci & 1) * 16;
                unsigned old = atomicAdd(&lc32[ci >> 1], 1u << sh);
                rank16[e0 + j] = (unsigned short)((old >> sh) & 0xFFFFu);
            }
            int ri = rw - base;
            if ((unsigned)ri < RANGE) atomicAdd(&ld[ri], we);
        }
    }
    __syncthreads();
    unsigned short* pcb = pc + (size_t)blockIdx.x * RANGE;
    float*          pdb = pd + (size_t)blockIdx.x * RANGE;
    for (int i = t; i < RANGE; i += HTHREADS) {
        pcb[i] = (unsigned short)((lc32[i >> 1] >> ((i & 1) * 16)) & 0xFFFFu);
        pdb[i] = ld[i];
    }
}

// ---- fold partials: dinv, per-slice prefix (pc in place), intra-block scan ----
__global__ __launch_bounds__(256) void reduce_kernel(
    unsigned short* __restrict__ pc, const float* __restrict__ pd,
    float* __restrict__ dinv, int* __restrict__ off, int* __restrict__ bsum)
{
    int t = threadIdx.x;
    int n = blockIdx.x * 256 + t;
    int c = 0; float d = 0.f;
    if (n < N_NODES) {
        int r = n / RANGE, i = n - r * RANGE;
        size_t base = (size_t)r * BPR * RANGE + i;
        unsigned csum = 0;
        for (int b = 0; b < BPR; ++b) {
            size_t idx = base + (size_t)b * RANGE;
            unsigned x = pc[idx];
            pc[idx] = (unsigned short)csum;
            csum += x;
            d += pd[idx];
        }
        c = (int)csum;
        dinv[n] = d > 0.f ? rsqrtf(d) : 0.f;
    }
    int lane = t & 63, wid = t >> 6;
    int v = c;
    for (int s = 1; s < 64; s <<= 1) {
        int u = __shfl_up(v, s);
        if (lane >= s) v += u;
    }
    __shared__ int ws[4];
    if (lane == 63) ws[wid] = v;
    __syncthreads();
    int wb = 0;
    for (int i = 0; i < 4; ++i) if (i < wid) wb += ws[i];
    int ex = (v - c) + wb;
    if (n < N_NODES) off[n] = ex;
    if (t == 255) bsum[blockIdx.x] = ex + c;
}

// ---- exclusive scan of 196 block sums ----
__global__ __launch_bounds__(256) void bsum_scan_kernel(
    int* __restrict__ bsum, int* __restrict__ off)
{
    int t = threadIdx.x;
    int orig = (t < NBLK) ? bsum[t] : 0;
    int lane = t & 63, wid = t >> 6;
    int v = orig;
    for (int s = 1; s < 64; s <<= 1) {
        int u = __shfl_up(v, s);
        if (lane >= s) v += u;
    }
    __shared__ int ws[4];
    if (lane == 63) ws[wid] = v;
    __syncthreads();
    int wb = 0;
    for (int i = 0; i < 4; ++i) if (i < wid) wb += ws[i];
    int ex = (v - orig) + wb;
    if (t < NBLK) bsum[t] = ex;
    if (t == NBLK - 1) off[N_NODES] = ex + orig;
}

// ---- add block prefix back ----
__global__ __launch_bounds__(256) void add_off_kernel(
    int* __restrict__ off, const int* __restrict__ bsum)
{
    int n = blockIdx.x * 256 + threadIdx.x;
    if (n < N_NODES) off[n] += bsum[n >> 8];
}

// ---- degree-sort perm, LDS-privatized (zero global atomics; output-invariant) ----
__global__ __launch_bounds__(256) void deg_count_kernel(
    const int* __restrict__ off, int* __restrict__ dpart)
{
    __shared__ int cnt[256];
    int t = threadIdx.x;
    cnt[t] = 0;
    __syncthreads();
    int n = blockIdx.x * 256 + t;
    if (n < N_NODES) {
        int d = off[n + 1] - off[n];
        if (d > 255) d = 255;
        atomicAdd(&cnt[d], 1);
    }
    __syncthreads();
    dpart[blockIdx.x * 256 + t] = cnt[t];
}
__global__ __launch_bounds__(256) void deg_scan_kernel(int* __restrict__ dpart)
{
    int t = threadIdx.x;            // bucket id
    int run = 0;
    for (int b = 0; b < NBLK; ++b) {
        int x = dpart[b * 256 + t];
        dpart[b * 256 + t] = run;
        run += x;
    }
    int lane = t & 63, wid = t >> 6;
    int v = run;
    for (int s = 1; s < 64; s <<= 1) {
        int u = __shfl_up(v, s);
        if (lane >= s) v += u;
    }
    __shared__ int ws[4];
    if (lane == 63) ws[wid] = v;
    __syncthreads();
    int wb = 0;
    for (int i = 0; i < 4; ++i) if (i < wid) wb += ws[i];
    int base = (v - run) + wb;
    for (int b = 0; b < NBLK; ++b) dpart[b * 256 + t] += base;
}
__global__ __launch_bounds__(256) void deg_scatter_kernel(
    const int* __restrict__ off, const int* __restrict__ dpart,
    int* __restrict__ perm)
{
    __shared__ int cnt[256];
    int t = threadIdx.x;
    cnt[t] = 0;
    __syncthreads();
    int n = blockIdx.x * 256 + t;
    if (n < N_NODES) {
        int d = off[n + 1] - off[n];
        if (d > 255) d = 255;
        int r = atomicAdd(&cnt[d], 1);          // LDS atomic
        perm[dpart[blockIdx.x * 256 + d] + r] = n;
    }
}

// ---- flat scatter: ONE pass over edges, packed 4B records, nt stores ----
__global__ __launch_bounds__(256) void scatter_flat_kernel(
    const int* __restrict__ row, const int* __restrict__ col,
    const float* __restrict__ w, const float* __restrict__ dinv,
    const int* __restrict__ off, const unsigned short* __restrict__ pc,
    const unsigned short* __restrict__ rank16, unsigned* __restrict__ edges)
{
    int tid = blockIdx.x * 256 + threadIdx.x;
    int e0 = tid * 4;
    if (e0 >= N_EDGES) return;
    int b = e0 / SLICE;
    int4   c4 = *(const int4*)&col[e0];
    int4   r4 = *(const int4*)&row[e0];
    float4 w4 = *(const float4*)&w[e0];
    ushort4 k4 = *(const ushort4*)&rank16[e0];
    #pragma unroll
    for (int j = 0; j < 4; ++j) {
        int c  = (j == 0) ? c4.x : (j == 1) ? c4.y : (j == 2) ? c4.z : c4.w;
        int rw = (j == 0) ? r4.x : (j == 1) ? r4.y : (j == 2) ? r4.z : r4.w;
        float we = (j == 0) ? w4.x : (j == 1) ? w4.y : (j == 2) ? w4.z : w4.w;
        int rk = (j == 0) ? k4.x : (j == 1) ? k4.y : (j == 2) ? k4.z : k4.w;
        int rg = c / RANGE;
        int clocal = c - rg * RANGE;
        int pre = pc[(size_t)(rg * BPR + b) * RANGE + clocal];
        float nr = -dinv[rw] * we * dinv[c];
        __half hn = __float2half_rn(nr);
        unsigned rec = (unsigned)rw |
                       ((unsigned)*reinterpret_cast<unsigned short*>(&hn) << 16);
        __builtin_nontemporal_store(rec, &edges[off[c] + pre + rk]);
    }
}

// ---- MFMA xf: xf = relu(x @ W_in + b_in) -> f32 d_out tail + padded fp16 T0 ----
__global__ __launch_bounds__(256) void xf_mfma_kernel(
    const float* __restrict__ x, const float* __restrict__ Win,
    const float* __restrict__ bin, float* __restrict__ xf_out,
    __half* __restrict__ T0h)
{
    __shared__ half8 Wf[3][4][64];   // 12288 B
    __shared__ float bs[EMB];
    int t = threadIdx.x;
    for (int idx = t; idx < 3 * 4 * 64; idx += 256) {
        int j = idx >> 8;
        int rem = idx & 255;
        int s = rem >> 6;
        int l = rem & 63;
        int colw = j * 16 + (l & 15);
        int k0 = s * 32 + (l >> 4) * 8;
        half8 v;
        #pragma unroll
        for (int i = 0; i < 8; ++i)
            v[i] = (_Float16)Win[(k0 + i) * EMB + colw];
        Wf[j][s][l] = v;
    }
    if (t < EMB) bs[t] = bin[t];
    __syncthreads();

    int wid = t >> 6, lane = t & 63;
    int nt = blockIdx.x * 4 + wid;
    if (nt >= NTILES) return;
    int n0 = nt * 16;
    int arow = lane & 15, kg = lane >> 4;

    const float* xr = x + (size_t)(n0 + arow) * F_IN + kg * 8;
    half8 a[4];
    #pragma unroll
    for (int s = 0; s < 4; ++s) {
        f32x4 lo = *reinterpret_cast<const f32x4*>(xr + s * 32);
        f32x4 hi = *reinterpret_cast<const f32x4*>(xr + s * 32 + 4);
        half8 av;
        av[0] = (_Float16)lo[0]; av[1] = (_Float16)lo[1];
        av[2] = (_Float16)lo[2]; av[3] = (_Float16)lo[3];
        av[4] = (_Float16)hi[0]; av[5] = (_Float16)hi[1];
        av[6] = (_Float16)hi[2]; av[7] = (_Float16)hi[3];
        a[s] = av;
    }

    f32x4 c0 = {0.f, 0.f, 0.f, 0.f}, c1 = c0, c2 = c0;
    #pragma unroll
    for (int s = 0; s < 4; ++s) {
        c0 = __builtin_amdgcn_mfma_f32_16x16x32_f16(a[s], Wf[0][s][lane], c0, 0, 0, 0);
        c1 = __builtin_amdgcn_mfma_f32_16x16x32_f16(a[s], Wf[1][s][lane], c1, 0, 0, 0);
        c2 = __builtin_amdgcn_mfma_f32_16x16x32_f16(a[s], Wf[2][s][lane], c2, 0, 0, 0);
    }

    int ccol = lane & 15;
    #pragma unroll
    for (int j = 0; j < 3; ++j) {
        int colg = j * 16 + ccol;
        float bias = bs[colg];
        f32x4 cj = (j == 0) ? c0 : (j == 1) ? c1 : c2;
        #pragma unroll
        for (int r = 0; r < 4; ++r) {
            int n = n0 + kg * 4 + r;
            float v = fmaxf(cj[r] + bias, 0.f);
            xf_out[(size_t)n * EMB + colg] = v;
            T0h[(size_t)n * TPAD + colg] = __float2half_rn(v);
        }
    }
    {
        int n = n0 + (lane >> 2);
        int cp = 48 + (lane & 3) * 4;
        *reinterpret_cast<uint2*>(T0h + (size_t)n * TPAD + cp) = make_uint2(0u, 0u);
    }
}

// ---- pure prop over degree-sorted node assignment (packed 4B edges) ----
// T-dst stores are nontemporal (2x b32): keeps T-src resident in L2.
__global__ __launch_bounds__(256) void prop_pure_kernel(
    const int* __restrict__ off, const unsigned* __restrict__ edges,
    const int* __restrict__ perm,
    const __half* __restrict__ tsrc, const __half* __restrict__ tprev,
    __half* __restrict__ tdst, int cheb_mode)
{
    int t = threadIdx.x;
    int grp = t >> 4, lane = t & 15;
    int g = perm[blockIdx.x * 16 + grp];

    float a0 = 0.f, a1 = 0.f, a2 = 0.f, a3 = 0.f;
    if (lane < 12) {
        int s = off[g], e = off[g + 1];
        int p = s;
        PROP_GATHER_LOOP(tsrc)
        if (cheb_mode) {
            uint2 tv = *reinterpret_cast<const uint2*>(tprev + (size_t)g * TPAD + 4 * lane);
            __half2 t01 = *reinterpret_cast<__half2*>(&tv.x);
            __half2 t23 = *reinterpret_cast<__half2*>(&tv.y);
            a0 = 2.f * a0 - __low2float(t01);
            a1 = 2.f * a1 - __high2float(t01);
            a2 = 2.f * a2 - __low2float(t23);
            a3 = 2.f * a3 - __high2float(t23);
        }
    }
    __half2 h01, h23;
    h01.x = __float2half_rn(a0); h01.y = __float2half_rn(a1);
    h23.x = __float2half_rn(a2); h23.y = __float2half_rn(a3);
    unsigned* dst = reinterpret_cast<unsigned*>(tdst + (size_t)g * TPAD + 4 * lane);
    __builtin_nontemporal_store(*reinterpret_cast<unsigned*>(&h01), dst);
    __builtin_nontemporal_store(*reinterpret_cast<unsigned*>(&h23), dst + 1);
}

// ---- out GEMM (MFMA): v = relu(sum_k T_k @ W_k + bch) -> padded f16 vAll ----
__global__ __launch_bounds__(HTHREADS) void out_mfma_kernel(
    const __half* __restrict__ Tall, const float* __restrict__ Wch,
    const float* __restrict__ bch, __half* __restrict__ vAll)
{
    __shared__ half8 Wf[3][KSL][64];   // 43008 B
    __shared__ float bchS[HID];
    int t = threadIdx.x;
    for (int idx = t; idx < 3 * KSL * 64; idx += HTHREADS) {
        int j = idx / (KSL * 64);
        int rem = idx - j * (KSL * 64);
        int s = rem >> 6;
        int l = rem & 63;
        int colw = j * 16 + (l & 15);
        int kch = s >> 1;
        int kbase = (s & 1) * 32 + (l >> 4) * 8;
        half8 v;
        #pragma unroll
        for (int i = 0; i < 8; ++i) {
            int kloc = kbase + i;
            v[i] = (kloc < EMB)
                 ? (_Float16)Wch[(size_t)kch * EMB * HID + kloc * HID + colw]
                 : (_Float16)0.f;
        }
        Wf[j][s][l] = v;
    }
    if (t < HID) bchS[t] = bch[t];
    __syncthreads();

    int wid = t >> 6, lane = t & 63;
    int nt = blockIdx.x * 8 + wid;
    if (nt >= NTILES) return;
    int n0 = nt * 16;
    int arow = lane & 15, kg = lane >> 4;
    int ccol = lane & 15;

    f32x4 c0 = {0.f, 0.f, 0.f, 0.f}, c1 = c0, c2 = c0;
    #pragma unroll
    for (int s = 0; s < KSL; ++s) {
        const __half* tp = Tall + (size_t)(s >> 1) * N_NODES * TPAD
                         + (size_t)(n0 + arow) * TPAD + (s & 1) * 32 + kg * 8;
        half8 af = *reinterpret_cast<const half8*>(tp);
        c0 = __builtin_amdgcn_mfma_f32_16x16x32_f16(af, Wf[0][s][lane], c0, 0, 0, 0);
        c1 = __builtin_amdgcn_mfma_f32_16x16x32_f16(af, Wf[1][s][lane], c1, 0, 0, 0);
        c2 = __builtin_amdgcn_mfma_f32_16x16x32_f16(af, Wf[2][s][lane], c2, 0, 0, 0);
    }
    #pragma unroll
    for (int j = 0; j < 3; ++j) {
        int colg = j * 16 + ccol;
        float bias = bchS[colg];
        f32x4 cj = (j == 0) ? c0 : (j == 1) ? c1 : c2;
        #pragma unroll
        for (int r = 0; r < 4; ++r)
            vAll[(size_t)(n0 + kg * 4 + r) * TPAD + colg] =
                __float2half_rn(fmaxf(cj[r] + bias, 0.f));
    }
    {
        int n = n0 + (lane >> 2);
        int cp = 48 + (lane & 3) * 4;
        *reinterpret_cast<uint2*>(vAll + (size_t)n * TPAD + cp) = make_uint2(0u, 0u);
    }
}

// ---- y GEMM (MFMA): y = vAll @ W_out + bout ----
__global__ __launch_bounds__(HTHREADS) void y_mfma_kernel(
    const __half* __restrict__ vAll, const float* __restrict__ Wout,
    const float* __restrict__ bout, float* __restrict__ y)
{
    __shared__ half8 Wo[4][2][64];   // 8192 B
    __shared__ float boS[OUTF];
    int t = threadIdx.x;
    for (int idx = t; idx < 4 * 2 * 64; idx += HTHREADS) {
        int jo = idx >> 7;
        int rem = idx & 127;
        int so = rem >> 6;
        int l = rem & 63;
        int colw = jo * 16 + (l & 15);
        int kbase = so * 32 + (l >> 4) * 8;
        half8 v;
        #pragma unroll
        for (int i = 0; i < 8; ++i) {
            int kloc = kbase + i;
            v[i] = (kloc < HID) ? (_Float16)Wout[kloc * OUTF + colw] : (_Float16)0.f;
        }
        Wo[jo][so][l] = v;
    }
    if (t < OUTF) boS[t] = bout[t];
    __syncthreads();

    int wid = t >> 6, lane = t & 63;
    int nt = blockIdx.x * 8 + wid;
    if (nt >= NTILES) return;
    int n0 = nt * 16;
    int arow = lane & 15, kg = lane >> 4;
    int ccol = lane & 15;

    f32x4 y0 = {0.f, 0.f, 0.f, 0.f}, y1 = y0, y2 = y0, y3 = y0;
    #pragma unroll
    for (int so = 0; so < 2; ++so) {
        half8 af = *reinterpret_cast<const half8*>(
            vAll + (size_t)(n0 + arow) * TPAD + so * 32 + kg * 8);
        y0 = __builtin_amdgcn_mfma_f32_16x16x32_f16(af, Wo[0][so][lane], y0, 0, 0, 0);
        y1 = __builtin_amdgcn_mfma_f32_16x16x32_f16(af, Wo[1][so][lane], y1, 0, 0, 0);
        y2 = __builtin_amdgcn_mfma_f32_16x16x32_f16(af, Wo[2][so][lane], y2, 0, 0, 0);
        y3 = __builtin_amdgcn_mfma_f32_16x16x32_f16(af, Wo[3][so][lane], y3, 0, 0, 0);
    }
    #pragma unroll
    for (int jo = 0; jo < 4; ++jo) {
        int colg = jo * 16 + ccol;
        float bias = boS[colg];
        f32x4 cj = (jo == 0) ? y0 : (jo == 1) ? y1 : (jo == 2) ? y2 : y3;
        #pragma unroll
        for (int r = 0; r < 4; ++r)
            y[(size_t)(n0 + kg * 4 + r) * OUTF + colg] = cj[r] + bias;
    }
}

extern "C" void kernel_launch(void* const* d_in, const int* in_sizes, int n_in,
                              void* d_out, int out_size, void* d_ws, size_t ws_size,
                              hipStream_t stream)
{
    const float* x    = (const float*)d_in[0];
    const int*   ei   = (const int*)d_in[1];
    const float* ew   = (const float*)d_in[2];
    const float* Win  = (const float*)d_in[3];
    const float* bin  = (const float*)d_in[4];
    const float* Wch  = (const float*)d_in[5];   // [7,48,48]
    const float* bch  = (const float*)d_in[6];
    const float* Wout = (const float*)d_in[7];
    const float* bout = (const float*)d_in[8];

    const int* row = ei;
    const int* col = ei + N_EDGES;

    float* y_out  = (float*)d_out;                           // [N,64]
    float* xf_out = (float*)d_out + (size_t)N_NODES * OUTF;  // [N,48]

    char* p = (char*)d_ws;
    auto carve = [&](size_t bytes) {
        void* q = p;
        p += (bytes + 255) & ~(size_t)255;
        return q;
    };
    unsigned short* pc = (unsigned short*)carve((size_t)NR * BPR * RANGE * 2); // 6.4 MB
    float*    pd  = (float*)carve((size_t)NR * BPR * RANGE * 4);               // 12.8 MB
    unsigned short* rank16 = (unsigned short*)carve((size_t)N_EDGES * 2);      // 3.2 MB
    float*    dinv = (float*)carve(N_NODES * 4);
    int*      off  = (int*)  carve((N_NODES + 1) * 4);
    int*      bsum = (int*)  carve(NBLK * 4);
    int*      dpart = (int*) carve((size_t)NBLK * 256 * 4);                    // 200 KB
    int*      perm = (int*)  carve(N_NODES * 4);
    unsigned* edges = (unsigned*)carve((size_t)N_EDGES * 4);                   // 6.4 MB
    __half*   Tall = (__half*)carve((size_t)KCH * N_NODES * TPAD * 2);         // 44.8 MB
    __half*   vAll = (__half*)carve((size_t)N_NODES * TPAD * 2);               // 6.4 MB

    // graph preprocessing — zero global atomics, packed 4B edge records
    hist_part_kernel<<<NR * BPR, HTHREADS, 0, stream>>>(row, col, ew, pc, pd, rank16);
    reduce_kernel<<<NBLK, 256, 0, stream>>>(pc, pd, dinv, off, bsum);
    bsum_scan_kernel<<<1, 256, 0, stream>>>(bsum, off);
    add_off_kernel<<<NBLK, 256, 0, stream>>>(off, bsum);
    deg_count_kernel<<<NBLK, 256, 0, stream>>>(off, dpart);
    deg_scan_kernel<<<1, 256, 0, stream>>>(dpart);
    deg_scatter_kernel<<<NBLK, 256, 0, stream>>>(off, dpart, perm);
    scatter_flat_kernel<<<(N_EDGES / 4 + 255) / 256, 256, 0, stream>>>(
        row, col, ew, dinv, off, pc, rank16, edges);

    // xf via MFMA -> f32 d_out tail + padded fp16 T0
    const size_t TSTR = (size_t)N_NODES * TPAD;
    xf_mfma_kernel<<<(NTILES + 3) / 4, 256, 0, stream>>>(x, Win, bin, xf_out, Tall);

    const int prop_grid = NTILES;   // 3125

    // T1 = prop(T0); Tk = 2*prop(T_{k-1}) - T_{k-2}, all pure, degree-sorted
    prop_pure_kernel<<<prop_grid, 256, 0, stream>>>(off, edges, perm, Tall, nullptr,
                                                    Tall + TSTR, 0);
    for (int k = 2; k < KCH; ++k) {
        prop_pure_kernel<<<prop_grid, 256, 0, stream>>>(
            off, edges, perm, Tall + (size_t)(k - 1) * TSTR, Tall + (size_t)(k - 2) * TSTR,
            Tall + (size_t)k * TSTR, 1);
    }

    // v = relu(sum_k Tk @ Wk + bch); y = v @ Wout + bout (all-MFMA, split)
    out_mfma_kernel<<<(NTILES + 7) / 8, HTHREADS, 0, stream>>>(Tall, Wch, bch, vAll);
    y_mfma_kernel<<<(NTILES + 7) / 8, HTHREADS, 0, stream>>>(vAll, Wout, bout, y_out);
}

// Round 26
// 283.535 us; speedup vs baseline: 1.0469x; 1.0469x over previous
//
#include <hip/hip_runtime.h>
#include <hip/hip_fp16.h>

#define N_NODES 50000
#define N_EDGES 1600000
#define F_IN    128
#define EMB     48
#define HID     48
#define OUTF    64
#define KCH     7
#define TPAD    64                   // padded T row length (halves) = 128 B
#define KSL     14                   // K-slices of 32 over 7*64 stacked T

#define NR    8                      // node ranges (LDS partitions)
#define RANGE (N_NODES / NR)         // 6250 counters
#define BPR   64                     // edge slices
#define SLICE (N_EDGES / BPR)        // 25000 edges per slice (div by 4)
#define HTHREADS 512
#define NBLK  ((N_NODES + 255) / 256)   // 196 blocks over nodes
#define NTILES (N_NODES / 16)        // 3125 node tiles

typedef __attribute__((ext_vector_type(8))) _Float16 half8;
typedef __attribute__((ext_vector_type(4))) float f32x4;

// ---- packed 4B edge record: low 16 = src (u16), high 16 = norm (f16) ----
__device__ __forceinline__ float dec_norm(unsigned er) {
    unsigned short h = (unsigned short)(er >> 16);
    return __half2float(*reinterpret_cast<__half*>(&h));
}

// ---- gather+accumulate (lane<12 only), unroll-16 / 4 / scalar ----
#define PROP_GATHER_LOOP(TSRC)                                                  \
    {                                                                           \
        int e16 = s + ((e - s) & ~15);                                          \
        for (; p < e16; p += 16) {                                              \
            float ww[16]; uint2 hv[16];                                         \
            _Pragma("unroll")                                                   \
            for (int j = 0; j < 16; ++j) {                                      \
                unsigned er = edges[p + j];                                     \
                ww[j] = dec_norm(er);                                           \
                hv[j] = *reinterpret_cast<const uint2*>(                        \
                    TSRC + (size_t)(er & 0xFFFFu) * TPAD + 4 * lane);           \
            }                                                                   \
            _Pragma("unroll")                                                   \
            for (int j = 0; j < 16; ++j) {                                      \
                __half2 h01 = *reinterpret_cast<__half2*>(&hv[j].x);            \
                __half2 h23 = *reinterpret_cast<__half2*>(&hv[j].y);            \
                a0 += ww[j] * __low2float(h01);                                 \
                a1 += ww[j] * __high2float(h01);                                \
                a2 += ww[j] * __low2float(h23);                                 \
                a3 += ww[j] * __high2float(h23);                                \
            }                                                                   \
        }                                                                       \
        int e4b = p + ((e - p) & ~3);                                           \
        for (; p < e4b; p += 4) {                                               \
            float ww[4]; uint2 hv[4];                                           \
            _Pragma("unroll")                                                   \
            for (int j = 0; j < 4; ++j) {                                       \
                unsigned er = edges[p + j];                                     \
                ww[j] = dec_norm(er);                                           \
                hv[j] = *reinterpret_cast<const uint2*>(                        \
                    TSRC + (size_t)(er & 0xFFFFu) * TPAD + 4 * lane);           \
            }                                                                   \
            _Pragma("unroll")                                                   \
            for (int j = 0; j < 4; ++j) {                                       \
                __half2 h01 = *reinterpret_cast<__half2*>(&hv[j].x);            \
                __half2 h23 = *reinterpret_cast<__half2*>(&hv[j].y);            \
                a0 += ww[j] * __low2float(h01);                                 \
                a1 += ww[j] * __high2float(h01);                                \
                a2 += ww[j] * __low2float(h23);                                 \
                a3 += ww[j] * __high2float(h23);                                \
            }                                                                   \
        }                                                                       \
        for (; p < e; ++p) {                                                    \
            unsigned er = edges[p];                                             \
            float wv = dec_norm(er);                                            \
            uint2 hv = *reinterpret_cast<const uint2*>(                         \
                TSRC + (size_t)(er & 0xFFFFu) * TPAD + 4 * lane);               \
            __half2 h01 = *reinterpret_cast<__half2*>(&hv.x);                   \
            __half2 h23 = *reinterpret_cast<__half2*>(&hv.y);                   \
            a0 += wv * __low2float(h01);                                        \
            a1 += wv * __high2float(h01);                                       \
            a2 += wv * __low2float(h23);                                        \
            a3 += wv * __high2float(h23);                                       \
        }                                                                       \
    }

// ---- pass A: partitioned LDS histogram; ALSO records per-edge rank (u16) ----
__global__ __launch_bounds__(HTHREADS) void hist_part_kernel(
    const int* __restrict__ row, const int* __restrict__ col,
    const float* __restrict__ w,
    unsigned short* __restrict__ pc, float* __restrict__ pd,
    unsigned short* __restrict__ rank16)
{
    __shared__ unsigned lc32[RANGE / 2];  // 12.5 KB
    __shared__ float    ld[RANGE];        // 25 KB
    int t = threadIdx.x;
    for (int i = t; i < RANGE / 2; i += HTHREADS) lc32[i] = 0u;
    for (int i = t; i < RANGE; i += HTHREADS) ld[i] = 0.f;
    __syncthreads();
    int r = blockIdx.x / BPR;        // node range
    int b = blockIdx.x % BPR;        // edge slice
    int base = r * RANGE;
    int lo = b * SLICE;
    for (int e0 = lo + t * 4; e0 < lo + SLICE; e0 += HTHREADS * 4) {
        int4   c4 = *(const int4*)&col[e0];
        int4   r4 = *(const int4*)&row[e0];
        float4 w4 = *(const float4*)&w[e0];
        #pragma unroll
        for (int j = 0; j < 4; ++j) {
            int c  = (j == 0) ? c4.x : (j == 1) ? c4.y : (j == 2) ? c4.z : c4.w;
            int rw = (j == 0) ? r4.x : (j == 1) ? r4.y : (j == 2) ? r4.z : r4.w;
            float we = (j == 0) ? w4.x : (j == 1) ? w4.y : (j == 2) ? w4.z : w4.w;
            int ci = c - base;
            if ((unsigned)ci < RANGE) {
                unsigned sh = (ci & 1) * 16;
                unsigned old = atomicAdd(&lc32[ci >> 1], 1u << sh);
                rank16[e0 + j] = (unsigned short)((old >> sh) & 0xFFFFu);
            }
            int ri = rw - base;
            if ((unsigned)ri < RANGE) atomicAdd(&ld[ri], we);
        }
    }
    __syncthreads();
    unsigned short* pcb = pc + (size_t)blockIdx.x * RANGE;
    float*          pdb = pd + (size_t)blockIdx.x * RANGE;
    for (int i = t; i < RANGE; i += HTHREADS) {
        pcb[i] = (unsigned short)((lc32[i >> 1] >> ((i & 1) * 16)) & 0xFFFFu);
        pdb[i] = ld[i];
    }
}

// ---- fold partials: dinv, per-slice prefix (pc in place), intra-block scan ----
__global__ __launch_bounds__(256) void reduce_kernel(
    unsigned short* __restrict__ pc, const float* __restrict__ pd,
    float* __restrict__ dinv, int* __restrict__ off, int* __restrict__ bsum)
{
    int t = threadIdx.x;
    int n = blockIdx.x * 256 + t;
    int c = 0; float d = 0.f;
    if (n < N_NODES) {
        int r = n / RANGE, i = n - r * RANGE;
        size_t base = (size_t)r * BPR * RANGE + i;
        unsigned csum = 0;
        for (int b = 0; b < BPR; ++b) {
            size_t idx = base + (size_t)b * RANGE;
            unsigned x = pc[idx];
            pc[idx] = (unsigned short)csum;
            csum += x;
            d += pd[idx];
        }
        c = (int)csum;
        dinv[n] = d > 0.f ? rsqrtf(d) : 0.f;
    }
    int lane = t & 63, wid = t >> 6;
    int v = c;
    for (int s = 1; s < 64; s <<= 1) {
        int u = __shfl_up(v, s);
        if (lane >= s) v += u;
    }
    __shared__ int ws[4];
    if (lane == 63) ws[wid] = v;
    __syncthreads();
    int wb = 0;
    for (int i = 0; i < 4; ++i) if (i < wid) wb += ws[i];
    int ex = (v - c) + wb;
    if (n < N_NODES) off[n] = ex;
    if (t == 255) bsum[blockIdx.x] = ex + c;
}

// ---- exclusive scan of 196 block sums ----
__global__ __launch_bounds__(256) void bsum_scan_kernel(
    int* __restrict__ bsum, int* __restrict__ off)
{
    int t = threadIdx.x;
    int orig = (t < NBLK) ? bsum[t] : 0;
    int lane = t & 63, wid = t >> 6;
    int v = orig;
    for (int s = 1; s < 64; s <<= 1) {
        int u = __shfl_up(v, s);
        if (lane >= s) v += u;
    }
    __shared__ int ws[4];
    if (lane == 63) ws[wid] = v;
    __syncthreads();
    int wb = 0;
    for (int i = 0; i < 4; ++i) if (i < wid) wb += ws[i];
    int ex = (v - orig) + wb;
    if (t < NBLK) bsum[t] = ex;
    if (t == NBLK - 1) off[N_NODES] = ex + orig;
}

// ---- add block prefix back ----
__global__ __launch_bounds__(256) void add_off_kernel(
    int* __restrict__ off, const int* __restrict__ bsum)
{
    int n = blockIdx.x * 256 + threadIdx.x;
    if (n < N_NODES) off[n] += bsum[n >> 8];
}

// ---- degree-sort perm, LDS-privatized (zero global atomics; output-invariant) ----
__global__ __launch_bounds__(256) void deg_count_kernel(
    const int* __restrict__ off, int* __restrict__ dpart)
{
    __shared__ int cnt[256];
    int t = threadIdx.x;
    cnt[t] = 0;
    __syncthreads();
    int n = blockIdx.x * 256 + t;
    if (n < N_NODES) {
        int d = off[n + 1] - off[n];
        if (d > 255) d = 255;
        atomicAdd(&cnt[d], 1);
    }
    __syncthreads();
    dpart[blockIdx.x * 256 + t] = cnt[t];
}
__global__ __launch_bounds__(256) void deg_scan_kernel(int* __restrict__ dpart)
{
    int t = threadIdx.x;            // bucket id
    int run = 0;
    for (int b = 0; b < NBLK; ++b) {
        int x = dpart[b * 256 + t];
        dpart[b * 256 + t] = run;
        run += x;
    }
    int lane = t & 63, wid = t >> 6;
    int v = run;
    for (int s = 1; s < 64; s <<= 1) {
        int u = __shfl_up(v, s);
        if (lane >= s) v += u;
    }
    __shared__ int ws[4];
    if (lane == 63) ws[wid] = v;
    __syncthreads();
    int wb = 0;
    for (int i = 0; i < 4; ++i) if (i < wid) wb += ws[i];
    int base = (v - run) + wb;
    for (int b = 0; b < NBLK; ++b) dpart[b * 256 + t] += base;
}
__global__ __launch_bounds__(256) void deg_scatter_kernel(
    const int* __restrict__ off, const int* __restrict__ dpart,
    int* __restrict__ perm)
{
    __shared__ int cnt[256];
    int t = threadIdx.x;
    cnt[t] = 0;
    __syncthreads();
    int n = blockIdx.x * 256 + t;
    if (n < N_NODES) {
        int d = off[n + 1] - off[n];
        if (d > 255) d = 255;
        int r = atomicAdd(&cnt[d], 1);          // LDS atomic
        perm[dpart[blockIdx.x * 256 + d] + r] = n;
    }
}

// ---- flat scatter: ONE pass over edges, packed 4B records ----
__global__ __launch_bounds__(256) void scatter_flat_kernel(
    const int* __restrict__ row, const int* __restrict__ col,
    const float* __restrict__ w, const float* __restrict__ dinv,
    const int* __restrict__ off, const unsigned short* __restrict__ pc,
    const unsigned short* __restrict__ rank16, unsigned* __restrict__ edges)
{
    int tid = blockIdx.x * 256 + threadIdx.x;
    int e0 = tid * 4;
    if (e0 >= N_EDGES) return;
    int b = e0 / SLICE;
    int4   c4 = *(const int4*)&col[e0];
    int4   r4 = *(const int4*)&row[e0];
    float4 w4 = *(const float4*)&w[e0];
    ushort4 k4 = *(const ushort4*)&rank16[e0];
    #pragma unroll
    for (int j = 0; j < 4; ++j) {
        int c  = (j == 0) ? c4.x : (j == 1) ? c4.y : (j == 2) ? c4.z : c4.w;
        int rw = (j == 0) ? r4.x : (j == 1) ? r4.y : (j == 2) ? r4.z : r4.w;
        float we = (j == 0) ? w4.x : (j == 1) ? w4.y : (j == 2) ? w4.z : w4.w;
        int rk = (j == 0) ? k4.x : (j == 1) ? k4.y : (j == 2) ? k4.z : k4.w;
        int rg = c / RANGE;
        int clocal = c - rg * RANGE;
        int pre = pc[(size_t)(rg * BPR + b) * RANGE + clocal];
        float nr = -dinv[rw] * we * dinv[c];
        __half hn = __float2half_rn(nr);
        unsigned rec = (unsigned)rw |
                       ((unsigned)*reinterpret_cast<unsigned short*>(&hn) << 16);
        edges[off[c] + pre + rk] = rec;
    }
}

// ---- MFMA xf: xf = relu(x @ W_in + b_in) -> f32 d_out tail + padded fp16 T0 ----
__global__ __launch_bounds__(256) void xf_mfma_kernel(
    const float* __restrict__ x, const float* __restrict__ Win,
    const float* __restrict__ bin, float* __restrict__ xf_out,
    __half* __restrict__ T0h)
{
    __shared__ half8 Wf[3][4][64];   // 12288 B
    __shared__ float bs[EMB];
    int t = threadIdx.x;
    for (int idx = t; idx < 3 * 4 * 64; idx += 256) {
        int j = idx >> 8;
        int rem = idx & 255;
        int s = rem >> 6;
        int l = rem & 63;
        int colw = j * 16 + (l & 15);
        int k0 = s * 32 + (l >> 4) * 8;
        half8 v;
        #pragma unroll
        for (int i = 0; i < 8; ++i)
            v[i] = (_Float16)Win[(k0 + i) * EMB + colw];
        Wf[j][s][l] = v;
    }
    if (t < EMB) bs[t] = bin[t];
    __syncthreads();

    int wid = t >> 6, lane = t & 63;
    int nt = blockIdx.x * 4 + wid;
    if (nt >= NTILES) return;
    int n0 = nt * 16;
    int arow = lane & 15, kg = lane >> 4;

    const float* xr = x + (size_t)(n0 + arow) * F_IN + kg * 8;
    half8 a[4];
    #pragma unroll
    for (int s = 0; s < 4; ++s) {
        f32x4 lo = *reinterpret_cast<const f32x4*>(xr + s * 32);
        f32x4 hi = *reinterpret_cast<const f32x4*>(xr + s * 32 + 4);
        half8 av;
        av[0] = (_Float16)lo[0]; av[1] = (_Float16)lo[1];
        av[2] = (_Float16)lo[2]; av[3] = (_Float16)lo[3];
        av[4] = (_Float16)hi[0]; av[5] = (_Float16)hi[1];
        av[6] = (_Float16)hi[2]; av[7] = (_Float16)hi[3];
        a[s] = av;
    }

    f32x4 c0 = {0.f, 0.f, 0.f, 0.f}, c1 = c0, c2 = c0;
    #pragma unroll
    for (int s = 0; s < 4; ++s) {
        c0 = __builtin_amdgcn_mfma_f32_16x16x32_f16(a[s], Wf[0][s][lane], c0, 0, 0, 0);
        c1 = __builtin_amdgcn_mfma_f32_16x16x32_f16(a[s], Wf[1][s][lane], c1, 0, 0, 0);
        c2 = __builtin_amdgcn_mfma_f32_16x16x32_f16(a[s], Wf[2][s][lane], c2, 0, 0, 0);
    }

    int ccol = lane & 15;
    #pragma unroll
    for (int j = 0; j < 3; ++j) {
        int colg = j * 16 + ccol;
        float bias = bs[colg];
        f32x4 cj = (j == 0) ? c0 : (j == 1) ? c1 : c2;
        #pragma unroll
        for (int r = 0; r < 4; ++r) {
            int n = n0 + kg * 4 + r;
            float v = fmaxf(cj[r] + bias, 0.f);
            xf_out[(size_t)n * EMB + colg] = v;
            T0h[(size_t)n * TPAD + colg] = __float2half_rn(v);
        }
    }
    {
        int n = n0 + (lane >> 2);
        int cp = 48 + (lane & 3) * 4;
        *reinterpret_cast<uint2*>(T0h + (size_t)n * TPAD + cp) = make_uint2(0u, 0u);
    }
}

// ---- pure prop over degree-sorted node assignment (packed 4B edges) ----
__global__ __launch_bounds__(256) void prop_pure_kernel(
    const int* __restrict__ off, const unsigned* __restrict__ edges,
    const int* __restrict__ perm,
    const __half* __restrict__ tsrc, const __half* __restrict__ tprev,
    __half* __restrict__ tdst, int cheb_mode)
{
    int t = threadIdx.x;
    int grp = t >> 4, lane = t & 15;
    int g = perm[blockIdx.x * 16 + grp];

    float a0 = 0.f, a1 = 0.f, a2 = 0.f, a3 = 0.f;
    if (lane < 12) {
        int s = off[g], e = off[g + 1];
        int p = s;
        PROP_GATHER_LOOP(tsrc)
        if (cheb_mode) {
            uint2 tv = *reinterpret_cast<const uint2*>(tprev + (size_t)g * TPAD + 4 * lane);
            __half2 t01 = *reinterpret_cast<__half2*>(&tv.x);
            __half2 t23 = *reinterpret_cast<__half2*>(&tv.y);
            a0 = 2.f * a0 - __low2float(t01);
            a1 = 2.f * a1 - __high2float(t01);
            a2 = 2.f * a2 - __low2float(t23);
            a3 = 2.f * a3 - __high2float(t23);
        }
    }
    __half2 h01, h23;
    h01.x = __float2half_rn(a0); h01.y = __float2half_rn(a1);
    h23.x = __float2half_rn(a2); h23.y = __float2half_rn(a3);
    uint2 ov;
    ov.x = *reinterpret_cast<unsigned*>(&h01);
    ov.y = *reinterpret_cast<unsigned*>(&h23);
    *reinterpret_cast<uint2*>(tdst + (size_t)g * TPAD + 4 * lane) = ov;
}

// ---- out GEMM (MFMA): v = relu(sum_k T_k @ W_k + bch) -> padded f16 vAll ----
__global__ __launch_bounds__(HTHREADS) void out_mfma_kernel(
    const __half* __restrict__ Tall, const float* __restrict__ Wch,
    const float* __restrict__ bch, __half* __restrict__ vAll)
{
    __shared__ half8 Wf[3][KSL][64];   // 43008 B
    __shared__ float bchS[HID];
    int t = threadIdx.x;
    for (int idx = t; idx < 3 * KSL * 64; idx += HTHREADS) {
        int j = idx / (KSL * 64);
        int rem = idx - j * (KSL * 64);
        int s = rem >> 6;
        int l = rem & 63;
        int colw = j * 16 + (l & 15);
        int kch = s >> 1;
        int kbase = (s & 1) * 32 + (l >> 4) * 8;
        half8 v;
        #pragma unroll
        for (int i = 0; i < 8; ++i) {
            int kloc = kbase + i;
            v[i] = (kloc < EMB)
                 ? (_Float16)Wch[(size_t)kch * EMB * HID + kloc * HID + colw]
                 : (_Float16)0.f;
        }
        Wf[j][s][l] = v;
    }
    if (t < HID) bchS[t] = bch[t];
    __syncthreads();

    int wid = t >> 6, lane = t & 63;
    int nt = blockIdx.x * 8 + wid;
    if (nt >= NTILES) return;
    int n0 = nt * 16;
    int arow = lane & 15, kg = lane >> 4;
    int ccol = lane & 15;

    f32x4 c0 = {0.f, 0.f, 0.f, 0.f}, c1 = c0, c2 = c0;
    #pragma unroll
    for (int s = 0; s < KSL; ++s) {
        const __half* tp = Tall + (size_t)(s >> 1) * N_NODES * TPAD
                         + (size_t)(n0 + arow) * TPAD + (s & 1) * 32 + kg * 8;
        half8 af = *reinterpret_cast<const half8*>(tp);
        c0 = __builtin_amdgcn_mfma_f32_16x16x32_f16(af, Wf[0][s][lane], c0, 0, 0, 0);
        c1 = __builtin_amdgcn_mfma_f32_16x16x32_f16(af, Wf[1][s][lane], c1, 0, 0, 0);
        c2 = __builtin_amdgcn_mfma_f32_16x16x32_f16(af, Wf[2][s][lane], c2, 0, 0, 0);
    }
    #pragma unroll
    for (int j = 0; j < 3; ++j) {
        int colg = j * 16 + ccol;
        float bias = bchS[colg];
        f32x4 cj = (j == 0) ? c0 : (j == 1) ? c1 : c2;
        #pragma unroll
        for (int r = 0; r < 4; ++r)
            vAll[(size_t)(n0 + kg * 4 + r) * TPAD + colg] =
                __float2half_rn(fmaxf(cj[r] + bias, 0.f));
    }
    {
        int n = n0 + (lane >> 2);
        int cp = 48 + (lane & 3) * 4;
        *reinterpret_cast<uint2*>(vAll + (size_t)n * TPAD + cp) = make_uint2(0u, 0u);
    }
}

// ---- y GEMM (MFMA): y = vAll @ W_out + bout ----
__global__ __launch_bounds__(HTHREADS) void y_mfma_kernel(
    const __half* __restrict__ vAll, const float* __restrict__ Wout,
    const float* __restrict__ bout, float* __restrict__ y)
{
    __shared__ half8 Wo[4][2][64];   // 8192 B
    __shared__ float boS[OUTF];
    int t = threadIdx.x;
    for (int idx = t; idx < 4 * 2 * 64; idx += HTHREADS) {
        int jo = idx >> 7;
        int rem = idx & 127;
        int so = rem >> 6;
        int l = rem & 63;
        int colw = jo * 16 + (l & 15);
        int kbase = so * 32 + (l >> 4) * 8;
        half8 v;
        #pragma unroll
        for (int i = 0; i < 8; ++i) {
            int kloc = kbase + i;
            v[i] = (kloc < HID) ? (_Float16)Wout[kloc * OUTF + colw] : (_Float16)0.f;
        }
        Wo[jo][so][l] = v;
    }
    if (t < OUTF) boS[t] = bout[t];
    __syncthreads();

    int wid = t >> 6, lane = t & 63;
    int nt = blockIdx.x * 8 + wid;
    if (nt >= NTILES) return;
    int n0 = nt * 16;
    int arow = lane & 15, kg = lane >> 4;
    int ccol = lane & 15;

    f32x4 y0 = {0.f, 0.f, 0.f, 0.f}, y1 = y0, y2 = y0, y3 = y0;
    #pragma unroll
    for (int so = 0; so < 2; ++so) {
        half8 af = *reinterpret_cast<const half8*>(
            vAll + (size_t)(n0 + arow) * TPAD + so * 32 + kg * 8);
        y0 = __builtin_amdgcn_mfma_f32_16x16x32_f16(af, Wo[0][so][lane], y0, 0, 0, 0);
        y1 = __builtin_amdgcn_mfma_f32_16x16x32_f16(af, Wo[1][so][lane], y1, 0, 0, 0);
        y2 = __builtin_amdgcn_mfma_f32_16x16x32_f16(af, Wo[2][so][lane], y2, 0, 0, 0);
        y3 = __builtin_amdgcn_mfma_f32_16x16x32_f16(af, Wo[3][so][lane], y3, 0, 0, 0);
    }
    #pragma unroll
    for (int jo = 0; jo < 4; ++jo) {
        int colg = jo * 16 + ccol;
        float bias = boS[colg];
        f32x4 cj = (jo == 0) ? y0 : (jo == 1) ? y1 : (jo == 2) ? y2 : y3;
        #pragma unroll
        for (int r = 0; r < 4; ++r)
            y[(size_t)(n0 + kg * 4 + r) * OUTF + colg] = cj[r] + bias;
    }
}

extern "C" void kernel_launch(void* const* d_in, const int* in_sizes, int n_in,
                              void* d_out, int out_size, void* d_ws, size_t ws_size,
                              hipStream_t stream)
{
    const float* x    = (const float*)d_in[0];
    const int*   ei   = (const int*)d_in[1];
    const float* ew   = (const float*)d_in[2];
    const float* Win  = (const float*)d_in[3];
    const float* bin  = (const float*)d_in[4];
    const float* Wch  = (const float*)d_in[5];   // [7,48,48]
    const float* bch  = (const float*)d_in[6];
    const float* Wout = (const float*)d_in[7];
    const float* bout = (const float*)d_in[8];

    const int* row = ei;
    const int* col = ei + N_EDGES;

    float* y_out  = (float*)d_out;                           // [N,64]
    float* xf_out = (float*)d_out + (size_t)N_NODES * OUTF;  // [N,48]

    char* p = (char*)d_ws;
    auto carve = [&](size_t bytes) {
        void* q = p;
        p += (bytes + 255) & ~(size_t)255;
        return q;
    };
    unsigned short* pc = (unsigned short*)carve((size_t)NR * BPR * RANGE * 2); // 6.4 MB
    float*    pd  = (float*)carve((size_t)NR * BPR * RANGE * 4);               // 12.8 MB
    unsigned short* rank16 = (unsigned short*)carve((size_t)N_EDGES * 2);      // 3.2 MB
    float*    dinv = (float*)carve(N_NODES * 4);
    int*      off  = (int*)  carve((N_NODES + 1) * 4);
    int*      bsum = (int*)  carve(NBLK * 4);
    int*      dpart = (int*) carve((size_t)NBLK * 256 * 4);                    // 200 KB
    int*      perm = (int*)  carve(N_NODES * 4);
    unsigned* edges = (unsigned*)carve((size_t)N_EDGES * 4);                   // 6.4 MB
    __half*   Tall = (__half*)carve((size_t)KCH * N_NODES * TPAD * 2);         // 44.8 MB
    __half*   vAll = (__half*)carve((size_t)N_NODES * TPAD * 2);               // 6.4 MB

    // graph preprocessing — zero global atomics, packed 4B edge records
    hist_part_kernel<<<NR * BPR, HTHREADS, 0, stream>>>(row, col, ew, pc, pd, rank16);
    reduce_kernel<<<NBLK, 256, 0, stream>>>(pc, pd, dinv, off, bsum);
    bsum_scan_kernel<<<1, 256, 0, stream>>>(bsum, off);
    add_off_kernel<<<NBLK, 256, 0, stream>>>(off, bsum);
    deg_count_kernel<<<NBLK, 256, 0, stream>>>(off, dpart);
    deg_scan_kernel<<<1, 256, 0, stream>>>(dpart);
    deg_scatter_kernel<<<NBLK, 256, 0, stream>>>(off, dpart, perm);
    scatter_flat_kernel<<<(N_EDGES / 4 + 255) / 256, 256, 0, stream>>>(
        row, col, ew, dinv, off, pc, rank16, edges);

    // xf via MFMA -> f32 d_out tail + padded fp16 T0
    const size_t TSTR = (size_t)N_NODES * TPAD;
    xf_mfma_kernel<<<(NTILES + 3) / 4, 256, 0, stream>>>(x, Win, bin, xf_out, Tall);

    const int prop_grid = NTILES;   // 3125

    // T1 = prop(T0); Tk = 2*prop(T_{k-1}) - T_{k-2}, all pure, degree-sorted
    prop_pure_kernel<<<prop_grid, 256, 0, stream>>>(off, edges, perm, Tall, nullptr,
                                                    Tall + TSTR, 0);
    for (int k = 2; k < KCH; ++k) {
        prop_pure_kernel<<<prop_grid, 256, 0, stream>>>(
            off, edges, perm, Tall + (size_t)(k - 1) * TSTR, Tall + (size_t)(k - 2) * TSTR,
            Tall + (size_t)k * TSTR, 1);
    }

    // v = relu(sum_k Tk @ Wk + bch); y = v @ Wout + bout (all-MFMA, split)
    out_mfma_kernel<<<(NTILES + 7) / 8, HTHREADS, 0, stream>>>(Tall, Wch, bch, vAll);
    y_mfma_kernel<<<(NTILES + 7) / 8, HTHREADS, 0, stream>>>(vAll, Wout, bout, y_out);
}